// Round 11
// baseline (502.086 us; speedup 1.0000x reference)
//
#include <hip/hip_runtime.h>
#include <hip/hip_bf16.h>
#include <stdint.h>

// Problem constants
#define BB 4
#define SS 2048
#define CC 1024
#define HH 16
#define DD 64
#define MTOT (BB*SS)      // 8192
#define NQKV 3072

typedef __attribute__((ext_vector_type(8))) short short8;   // 8 bf16 (4 VGPRs)
typedef __attribute__((ext_vector_type(4))) float f32x4;    // MFMA accumulator

#define MFMA16(A,B,C) __builtin_amdgcn_mfma_f32_16x16x32_bf16((A),(B),(C),0,0,0)
#define BARRIER() asm volatile("s_barrier" ::: "memory")

__device__ __forceinline__ ushort f2bf(float f) {
  uint32_t u = __builtin_bit_cast(uint32_t, f);
  u += 0x7FFFu + ((u >> 16) & 1u);   // round-to-nearest-even
  return (ushort)(u >> 16);
}

__device__ __forceinline__ float bf2f(ushort u) {
  return __builtin_bit_cast(float, (uint32_t)u << 16);
}

__device__ __forceinline__ unsigned cvtpk(float lo, float hi) {
  unsigned r;
  asm("v_cvt_pk_bf16_f32 %0, %1, %2" : "=v"(r) : "v"(lo), "v"(hi));
  return r;
}

__device__ __forceinline__ float hw_exp2(float x) {
  float r;
  asm("v_exp_f32 %0, %1" : "=v"(r) : "v"(x));
  return r;
}

// ---------------- merged f32 -> bf16 conversion (x, W_qkv, W_out in one launch) ------------
__global__ void cvt3_kernel(const float* __restrict__ a, ushort* __restrict__ da, int na4,
                            const float* __restrict__ b, ushort* __restrict__ db, int nb4,
                            const float* __restrict__ c, ushort* __restrict__ dc, int nc4) {
  int total = na4 + nb4 + nc4;
  int stride = gridDim.x * blockDim.x;
  for (int i = blockIdx.x * blockDim.x + threadIdx.x; i < total; i += stride) {
    const float4* s; ushort4* d; int k;
    if (i < na4)            { s = (const float4*)a; d = (ushort4*)da; k = i; }
    else if (i < na4 + nb4) { s = (const float4*)b; d = (ushort4*)db; k = i - na4; }
    else                    { s = (const float4*)c; d = (ushort4*)dc; k = i - na4 - nb4; }
    float4 v = s[k];
    ushort4 o;
    o.x = f2bf(v.x); o.y = f2bf(v.y); o.z = f2bf(v.z); o.w = f2bf(v.w);
    d[k] = o;
  }
}

// ======== GEMM core: 128x128 tile, BK=64, 4 waves, dbuf LDS 64KB, counted vmcnt ========
__device__ __forceinline__ void stage_half128(const ushort* __restrict__ gsrc, ushort* ldsbase, int tid) {
  #pragma unroll
  for (int ld = 0; ld < 4; ++ld) {
    int ci = ld * 256 + tid;                  // 16B chunk 0..1023 (128 rows x 8 slots)
    int row = ci >> 3, slot = ci & 7;
    const ushort* src = gsrc + (size_t)row * 1024 + ((slot ^ (row & 7)) << 3);
    __builtin_amdgcn_global_load_lds(
        (const __attribute__((address_space(1))) uint32_t*)src,
        (__attribute__((address_space(3))) uint32_t*)(ldsbase + ci * 8), 16, 0, 0);
  }
}

__device__ __forceinline__ short8 rd_frag(const ushort* Lb, int row, int slot) {
  return *(const short8*)(Lb + row * 64 + ((slot ^ (row & 7)) << 3));
}

__device__ __forceinline__ void core128(const ushort* __restrict__ A, const ushort* __restrict__ Bw,
                                        int m0, int n0, ushort* L, f32x4 acc[4][4]) {
  const int tid = threadIdx.x, lane = tid & 63, w = tid >> 6;
  const int q = lane & 15, g = lane >> 4;
  const int wm = (w >> 1) * 64, wn = (w & 1) * 64;
  const ushort* Ag = A + (size_t)m0 * 1024;
  const ushort* Bg = Bw + (size_t)n0 * 1024;

  #pragma unroll
  for (int tt = 0; tt < 2; ++tt) {
    stage_half128(Ag + tt * 64, L + tt * 16384, tid);
    stage_half128(Bg + tt * 64, L + tt * 16384 + 8192, tid);
  }
  asm volatile("s_waitcnt vmcnt(8)" ::: "memory");   // tile 0 landed (tile 1 in flight)
  BARRIER();

  #pragma unroll 1
  for (int t = 0; t < 16; ++t) {
    const ushort* La = L + (t & 1) * 16384;
    const ushort* Lb = La + 8192;
    short8 af[4][2], bf[4][2];
    #pragma unroll
    for (int mi = 0; mi < 4; ++mi)
      #pragma unroll
      for (int ks = 0; ks < 2; ++ks)
        af[mi][ks] = rd_frag(La, wm + mi * 16 + q, ks * 4 + g);
    #pragma unroll
    for (int nj = 0; nj < 4; ++nj)
      #pragma unroll
      for (int ks = 0; ks < 2; ++ks)
        bf[nj][ks] = rd_frag(Lb, wn + nj * 16 + q, ks * 4 + g);
    #pragma unroll
    for (int mi = 0; mi < 4; ++mi)
      #pragma unroll
      for (int nj = 0; nj < 4; ++nj) {
        acc[mi][nj] = MFMA16(af[mi][0], bf[nj][0], acc[mi][nj]);
        acc[mi][nj] = MFMA16(af[mi][1], bf[nj][1], acc[mi][nj]);
      }
    BARRIER();                                      // all waves done reading buf (t&1)
    if (t <= 13) {
      ushort* Ls = L + (t & 1) * 16384;             // overwrite-safe: last read barrier'd above
      stage_half128(Ag + (t + 2) * 64, Ls, tid);
      stage_half128(Bg + (t + 2) * 64, Ls + 8192, tid);
      asm volatile("s_waitcnt vmcnt(8)" ::: "memory");  // tile t+1 landed; t+2's 8 in flight
      BARRIER();
    } else if (t == 14) {
      asm volatile("s_waitcnt vmcnt(0)" ::: "memory");  // tile 15 landed
      BARRIER();
    }
  }
}

// ---------------- GEMM1: qkv = x @ W_qkv^T, LDS-restaged coalesced scatter ----------------
// QF/KF layout: [bh][jt=s>>4][c0=c>>5][lane2(64)][e=c&7]   lane2=((c>>3)&3)*16+(s&15)
// VF layout:    [bh][jc=s>>5][ct=c>>4][lane(64)=((s>>3)&3)*16+(c&15)][e=s&7]
__global__ __launch_bounds__(256, 2) void gemm_qkv(const ushort* __restrict__ xb, const ushort* __restrict__ wqkv,
                                                   ushort* __restrict__ qfbuf, ushort* __restrict__ kfbuf,
                                                   ushort* __restrict__ vfbuf) {
  __shared__ __align__(16) ushort L[32768];   // 64 KB -> 2 blocks/CU
  const int bid = blockIdx.x;                 // 1536 = 8 XCD * (64 m * 3 n); n fastest per XCD
  const int xcd = bid & 7, r0 = bid >> 3;
  const int m0 = (r0 / 3) * 128, n0 = (xcd * 3 + (r0 % 3)) * 128;

  f32x4 acc[4][4];
  #pragma unroll
  for (int i = 0; i < 4; ++i)
    #pragma unroll
    for (int j = 0; j < 4; ++j) acc[i][j] = f32x4{0.f, 0.f, 0.f, 0.f};
  core128(xb, wqkv, m0, n0, L, acc);

  const int lane = threadIdx.x & 63, wave = threadIdx.x >> 6;
  const int g = lane >> 4, q = lane & 15;
  const int wm = (wave >> 1) * 64, wn = (wave & 1) * 64;
  const int s0 = m0 & 2047, bb = m0 >> 11;

  // ---- write phase: C/D (col=q, row=g*4+r) -> LDS [mr][nc ^ ((mr&7)<<4)], bf16
  #pragma unroll
  for (int j = 0; j < 4; ++j) {
    int n = n0 + wn + j * 16 + q;
    int h = n / 192;
    int which = (n - h * 192) >> 6;
    float scl = (which == 0) ? 0.045084222f : 1.0f;   // 1/sqrt(C)*log2(e) folded into Q
    int nc = wn + j * 16 + q;
    #pragma unroll
    for (int i = 0; i < 4; ++i) {
      #pragma unroll
      for (int rr = 0; rr < 4; ++rr) {
        int mr = wm + i * 16 + g * 4 + rr;
        L[mr * 128 + (nc ^ ((mr & 7) << 4))] = f2bf(acc[i][j][rr] * scl);
      }
    }
  }
  __syncthreads();

  // ---- read+store phase: wave w owns n-octet-group [n0+32w, +32) (which/h wave-uniform)
  {
    const int n_g = n0 + wave * 32;
    const int h = n_g / 192, rem = n_g - h * 192, which = rem >> 6;
    const int bh = bb * 16 + h;
    if (which < 2) {
      ushort* dst0 = (which == 0) ? qfbuf : kfbuf;
      const int c0 = (rem & 63) >> 5;
      #pragma unroll
      for (int k = 0; k < 8; ++k) {
        int jt = (s0 >> 4) + k;
        int mr = k * 16 + (lane & 15);
        int nc0 = wave * 32 + (lane >> 4) * 8;
        short8 v = *(const short8*)(L + mr * 128 + (nc0 ^ ((mr & 7) << 4)));
        *(short8*)(dst0 + ((((size_t)bh * 128 + jt) * 2 + c0) * 64 + lane) * 8) = v;
      }
    } else {
      const int ct0 = (rem & 63) >> 4;
      #pragma unroll
      for (int k = 0; k < 8; ++k) {
        int jcr = k >> 1, ct = ct0 + (k & 1);
        int nc = wave * 32 + (k & 1) * 16 + (lane & 15);
        int mrb = jcr * 32 + (lane >> 4) * 8;
        short8 v;
        #pragma unroll
        for (int e = 0; e < 8; ++e) {
          int mr = mrb + e;
          v[e] = (short)L[mr * 128 + (nc ^ ((mr & 7) << 4))];
        }
        int jc = (s0 >> 5) + jcr;
        *(short8*)(vfbuf + ((((size_t)bh * 64 + jc) * 4 + ct) * 64 + lane) * 8) = v;
      }
    }
  }
}

// ---------------- GEMM2: out = attn_out @ W_out^T + b_out + x (f32 out, coalesced) --------
__global__ __launch_bounds__(256, 2) void gemm_out(const ushort* __restrict__ ab, const ushort* __restrict__ wout,
                                                   const ushort* __restrict__ xbb, const float* __restrict__ bias,
                                                   float* __restrict__ out) {
  __shared__ __align__(16) ushort L[32768];
  const int bid = blockIdx.x;                 // 512 = 8 * 64 ; 1 n-panel per XCD
  const int sw = (bid & 7) * 64 + (bid >> 3);
  const int m0 = (sw & 63) * 128, n0 = (sw >> 6) * 128;

  f32x4 acc[4][4];
  #pragma unroll
  for (int i = 0; i < 4; ++i)
    #pragma unroll
    for (int j = 0; j < 4; ++j) acc[i][j] = f32x4{0.f, 0.f, 0.f, 0.f};
  core128(ab, wout, m0, n0, L, acc);

  const int tid = threadIdx.x;
  const int lane = tid & 63, wave = tid >> 6;
  const int g = lane >> 4, q = lane & 15;
  const int wm = (wave >> 1) * 64, wn = (wave & 1) * 64;
  float* Lf = reinterpret_cast<float*>(L);    // 128x128 f32 = 64KB (core128 ended barrier'd)

  // write phase: swz col' = col ^ (bit2(row)<<2) ^ (bit3(row)<<4): 2-way max, float4-safe
  #pragma unroll
  for (int j = 0; j < 4; ++j) {
    int nc = wn + j * 16 + q;
    #pragma unroll
    for (int i = 0; i < 4; ++i) {
      #pragma unroll
      for (int rr = 0; rr < 4; ++rr) {
        int mr = wm + i * 16 + g * 4 + rr;
        int swz = ((mr & 4) << 0) | ((mr & 8) << 1);   // bits {2,4}
        Lf[mr * 128 + (nc ^ swz)] = acc[i][j][rr];
      }
    }
  }
  __syncthreads();

  // read+store phase: fully coalesced float4 stores + bf16 residual + bias
  #pragma unroll
  for (int k = 0; k < 16; ++k) {
    int ci = k * 256 + tid;          // 0..4095 = 128 rows x 32 col-chunks
    int row = ci >> 5, cb = (ci & 31) * 4;
    int swz = ((row & 4) << 0) | ((row & 8) << 1);
    float4 v = *(const float4*)(Lf + row * 128 + (cb ^ swz));
    size_t m = (size_t)(m0 + row);
    int n = n0 + cb;
    ushort4 xr = *(const ushort4*)(xbb + m * 1024 + n);
    float4 bv = *(const float4*)(bias + n);
    float4 o;
    o.x = v.x + bv.x + bf2f(xr.x);
    o.y = v.y + bv.y + bf2f(xr.y);
    o.z = v.z + bv.z + bf2f(xr.z);
    o.w = v.w + bv.w + bf2f(xr.w);
    *(float4*)(out + m * 1024 + n) = o;
  }
}

// ---------------- Flash attention v6: T15 double-pipeline (PV one step late) -----------------
__device__ __forceinline__ void qk_pack(const short8 kf[4][2], const short8 qf[2][2],
                                        ushort* pwPar, int g, int q) {
  const f32x4 zed = {0.f, 0.f, 0.f, 0.f};
  #pragma unroll
  for (int t = 0; t < 2; ++t) {
    f32x4 sa[4];
    __builtin_amdgcn_s_setprio(1);
    #pragma unroll
    for (int jt = 0; jt < 4; ++jt) {
      sa[jt] = MFMA16(kf[jt][0], qf[t][0], zed);
      sa[jt] = MFMA16(kf[jt][1], qf[t][1], sa[jt]);
    }
    __builtin_amdgcn_s_setprio(0);
    ushort* pw = pwPar + t * 1152;
    #pragma unroll
    for (int jt = 0; jt < 4; ++jt) {
      uint2 wv;
      wv.x = cvtpk(hw_exp2(sa[jt][0]), hw_exp2(sa[jt][1]));
      wv.y = cvtpk(hw_exp2(sa[jt][2]), hw_exp2(sa[jt][3]));
      *reinterpret_cast<uint2*>(pw + q * 72 + jt * 16 + 4 * g) = wv;
    }
  }
}

__device__ __forceinline__ void pv_acc(const short8 vf[2][4], const ushort* pwPar,
                                       const short8 onesf, f32x4 oa[2][4], f32x4 la[2],
                                       int g, int q) {
  #pragma unroll
  for (int t = 0; t < 2; ++t) {
    const ushort* pw = pwPar + t * 1152;
    #pragma unroll
    for (int jc = 0; jc < 2; ++jc) {
      short8 pa = *reinterpret_cast<const short8*>(pw + q * 72 + jc * 32 + g * 8);
      __builtin_amdgcn_s_setprio(1);
      #pragma unroll
      for (int ct = 0; ct < 4; ++ct)
        oa[t][ct] = MFMA16(pa, vf[jc][ct], oa[t][ct]);
      la[t] = MFMA16(pa, onesf, la[t]);
      __builtin_amdgcn_s_setprio(0);
    }
  }
}

__global__ __launch_bounds__(256, 3) void attn_kernel(const ushort* __restrict__ QF, const ushort* __restrict__ KF,
                                                      const ushort* __restrict__ VF, ushort* __restrict__ aout) {
  __shared__ ushort Ps[4][2][2 * 1152];   // [wave][step-parity][t*1152]; 36 KB
  // grid: 1024 1-D. Per XCD (bid&7): qb cycles fastest -> ~1-2 bh's K/V L2-hot.
  const int bid = blockIdx.x;
  const int xcd = bid & 7, rr = bid >> 3;
  const int qb = rr & 15, bh = xcd + (rr >> 4) * 8;
  const int lane = threadIdx.x & 63, wave = threadIdx.x >> 6;
  const int g = lane >> 4, q = lane & 15;
  const int qt0 = (qb * 4 + wave) * 2;
  const f32x4 zed = {0.f, 0.f, 0.f, 0.f};

  const ushort* Qb = QF + (size_t)bh * 131072 + lane * 8;
  const ushort* Kp = KF + (size_t)bh * 131072 + lane * 8;
  const ushort* Vp = VF + (size_t)bh * 131072 + lane * 8;

  short8 onesf;
  #pragma unroll
  for (int e = 0; e < 8; ++e) onesf[e] = (short)0x3F80;

  short8 qf[2][2];
  #pragma unroll
  for (int t = 0; t < 2; ++t)
    #pragma unroll
    for (int c0 = 0; c0 < 2; ++c0)
      qf[t][c0] = *(const short8*)(Qb + ((size_t)(qt0 + t) * 2 + c0) * 512);

  f32x4 oa[2][4], la[2];
  #pragma unroll
  for (int t = 0; t < 2; ++t) {
    la[t] = zed;
    #pragma unroll
    for (int ct = 0; ct < 4; ++ct) oa[t][ct] = zed;
  }

  short8 kfA[4][2], kfB[4][2], vfA[2][4], vfB[2][4];
  #pragma unroll
  for (int jt = 0; jt < 4; ++jt)
    #pragma unroll
    for (int c0 = 0; c0 < 2; ++c0)
      kfA[jt][c0] = *(const short8*)(Kp + ((size_t)jt * 2 + c0) * 512);

  #pragma unroll 1
  for (int ii = 0; ii < 32; ii += 2) {
    // half A = step ii (parity 0)
    #pragma unroll
    for (int jc = 0; jc < 2; ++jc)
      #pragma unroll
      for (int ct = 0; ct < 4; ++ct)
        vfA[jc][ct] = *(const short8*)(Vp + ((size_t)jc * 4 + ct) * 512);    // V(ii), used half B
    #pragma unroll
    for (int jt = 0; jt < 4; ++jt)
      #pragma unroll
      for (int c0 = 0; c0 < 2; ++c0)
        kfB[jt][c0] = *(const short8*)(Kp + 4096 + ((size_t)jt * 2 + c0) * 512);

    qk_pack(kfA, qf, Ps[wave][0], g, q);                       // P(ii) -> parity 0
    if (ii > 0) pv_acc(vfB, Ps[wave][1], onesf, oa, la, g, q); // PV(ii-1): V(ii-1), P parity 1

    // half B = step ii+1 (parity 1)
    #pragma unroll
    for (int jc = 0; jc < 2; ++jc)
      #pragma unroll
      for (int ct = 0; ct < 4; ++ct)
        vfB[jc][ct] = *(const short8*)(Vp + 4096 + ((size_t)jc * 4 + ct) * 512);  // V(ii+1)
    if (ii + 2 < 32) {
      #pragma unroll
      for (int jt = 0; jt < 4; ++jt)
        #pragma unroll
        for (int c0 = 0; c0 < 2; ++c0)
          kfA[jt][c0] = *(const short8*)(Kp + 8192 + ((size_t)jt * 2 + c0) * 512);
    }

    qk_pack(kfB, qf, Ps[wave][1], g, q);                       // P(ii+1) -> parity 1
    pv_acc(vfA, Ps[wave][0], onesf, oa, la, g, q);             // PV(ii): V(ii), P parity 0

    Kp += 8192; Vp += 8192;
  }
  pv_acc(vfB, Ps[wave][1], onesf, oa, la, g, q);               // PV(31): V(31), P parity 1

  const int b = bh >> 4, h = bh & 15;
  #pragma unroll
  for (int t = 0; t < 2; ++t) {
    float inv[4];
    #pragma unroll
    for (int r2 = 0; r2 < 4; ++r2) inv[r2] = 1.0f / la[t][r2];
    #pragma unroll
    for (int ct = 0; ct < 4; ++ct) {
      size_t rowb = (size_t)b * SS + (qt0 + t) * 16 + 4 * g;
      int col = h * DD + ct * 16 + q;
      aout[(rowb + 0) * CC + col] = f2bf(oa[t][ct][0] * inv[0]);
      aout[(rowb + 1) * CC + col] = f2bf(oa[t][ct][1] * inv[1]);
      aout[(rowb + 2) * CC + col] = f2bf(oa[t][ct][2] * inv[2]);
      aout[(rowb + 3) * CC + col] = f2bf(oa[t][ct][3] * inv[3]);
    }
  }
}

extern "C" void kernel_launch(void* const* d_in, const int* in_sizes, int n_in,
                              void* d_out, int out_size, void* d_ws, size_t ws_size,
                              hipStream_t stream) {
  const float* x    = (const float*)d_in[0];   // [4,2048,1024]
  const float* wqkv = (const float*)d_in[1];   // [3072,1024]
  const float* wout = (const float*)d_in[2];   // [1024,1024]
  const float* bias = (const float*)d_in[3];   // [1024]
  float* out = (float*)d_out;

  // workspace carve (ushort elements), total 44M elems = 88MB
  ushort* xb    = (ushort*)d_ws;                   // 8M
  ushort* wqkvb = xb + (size_t)8 * 1024 * 1024;    // 3M
  ushort* woutb = wqkvb + (size_t)3 * 1024 * 1024; // 1M
  ushort* qfbuf = woutb + (size_t)1024 * 1024;     // 8M
  ushort* kfbuf = qfbuf + (size_t)8 * 1024 * 1024; // 8M
  ushort* vfbuf = kfbuf + (size_t)8 * 1024 * 1024; // 8M
  ushort* aout  = vfbuf + (size_t)8 * 1024 * 1024; // 8M

  hipLaunchKernelGGL(cvt3_kernel, dim3(2048), dim3(256), 0, stream,
                     x, xb, 8 * 1024 * 1024 / 4,
                     wqkv, wqkvb, 3 * 1024 * 1024 / 4,
                     wout, woutb, 1024 * 1024 / 4);

  hipLaunchKernelGGL(gemm_qkv, dim3(1536), dim3(256), 0, stream,
                     xb, wqkvb, qfbuf, kfbuf, vfbuf);
  hipLaunchKernelGGL(attn_kernel, dim3(1024), dim3(256), 0, stream,
                     qfbuf, kfbuf, vfbuf, aout);
  hipLaunchKernelGGL(gemm_out, dim3(512), dim3(256), 0, stream,
                     aout, woutb, xb, bias, out);
}

// Round 12
// 190.887 us; speedup vs baseline: 2.6303x; 2.6303x over previous
//
#include <hip/hip_runtime.h>
#include <hip/hip_bf16.h>
#include <stdint.h>

// Problem constants
#define BB 4
#define SS 2048
#define CC 1024
#define HH 16
#define DD 64
#define MTOT (BB*SS)      // 8192
#define NQKV 3072

typedef __attribute__((ext_vector_type(8))) short short8;   // 8 bf16 (4 VGPRs)
typedef __attribute__((ext_vector_type(4))) float f32x4;    // MFMA accumulator

#define MFMA16(A,B,C) __builtin_amdgcn_mfma_f32_16x16x32_bf16((A),(B),(C),0,0,0)
#define BARRIER() asm volatile("s_barrier" ::: "memory")

__device__ __forceinline__ ushort f2bf(float f) {
  uint32_t u = __builtin_bit_cast(uint32_t, f);
  u += 0x7FFFu + ((u >> 16) & 1u);   // round-to-nearest-even
  return (ushort)(u >> 16);
}

__device__ __forceinline__ float bf2f(ushort u) {
  return __builtin_bit_cast(float, (uint32_t)u << 16);
}

__device__ __forceinline__ unsigned cvtpk(float lo, float hi) {
  unsigned r;
  asm("v_cvt_pk_bf16_f32 %0, %1, %2" : "=v"(r) : "v"(lo), "v"(hi));
  return r;
}

__device__ __forceinline__ float hw_exp2(float x) {
  float r;
  asm("v_exp_f32 %0, %1" : "=v"(r) : "v"(x));
  return r;
}

// ---------------- merged f32 -> bf16 conversion (x, W_qkv, W_out in one launch) ------------
__global__ void cvt3_kernel(const float* __restrict__ a, ushort* __restrict__ da, int na4,
                            const float* __restrict__ b, ushort* __restrict__ db, int nb4,
                            const float* __restrict__ c, ushort* __restrict__ dc, int nc4) {
  int total = na4 + nb4 + nc4;
  int stride = gridDim.x * blockDim.x;
  for (int i = blockIdx.x * blockDim.x + threadIdx.x; i < total; i += stride) {
    const float4* s; ushort4* d; int k;
    if (i < na4)            { s = (const float4*)a; d = (ushort4*)da; k = i; }
    else if (i < na4 + nb4) { s = (const float4*)b; d = (ushort4*)db; k = i - na4; }
    else                    { s = (const float4*)c; d = (ushort4*)dc; k = i - na4 - nb4; }
    float4 v = s[k];
    ushort4 o;
    o.x = f2bf(v.x); o.y = f2bf(v.y); o.z = f2bf(v.z); o.w = f2bf(v.w);
    d[k] = o;
  }
}

// ======== GEMM core: 128x128 tile, BK=64, 4 waves, dbuf LDS 64KB, counted vmcnt ========
__device__ __forceinline__ void stage_half128(const ushort* __restrict__ gsrc, ushort* ldsbase, int tid) {
  #pragma unroll
  for (int ld = 0; ld < 4; ++ld) {
    int ci = ld * 256 + tid;                  // 16B chunk 0..1023 (128 rows x 8 slots)
    int row = ci >> 3, slot = ci & 7;
    const ushort* src = gsrc + (size_t)row * 1024 + ((slot ^ (row & 7)) << 3);
    __builtin_amdgcn_global_load_lds(
        (const __attribute__((address_space(1))) uint32_t*)src,
        (__attribute__((address_space(3))) uint32_t*)(ldsbase + ci * 8), 16, 0, 0);
  }
}

__device__ __forceinline__ short8 rd_frag(const ushort* Lb, int row, int slot) {
  return *(const short8*)(Lb + row * 64 + ((slot ^ (row & 7)) << 3));
}

__device__ __forceinline__ void core128(const ushort* __restrict__ A, const ushort* __restrict__ Bw,
                                        int m0, int n0, ushort* L, f32x4 acc[4][4]) {
  const int tid = threadIdx.x, lane = tid & 63, w = tid >> 6;
  const int q = lane & 15, g = lane >> 4;
  const int wm = (w >> 1) * 64, wn = (w & 1) * 64;
  const ushort* Ag = A + (size_t)m0 * 1024;
  const ushort* Bg = Bw + (size_t)n0 * 1024;

  #pragma unroll
  for (int tt = 0; tt < 2; ++tt) {
    stage_half128(Ag + tt * 64, L + tt * 16384, tid);
    stage_half128(Bg + tt * 64, L + tt * 16384 + 8192, tid);
  }
  asm volatile("s_waitcnt vmcnt(8)" ::: "memory");   // tile 0 landed (tile 1 in flight)
  BARRIER();

  #pragma unroll 1
  for (int t = 0; t < 16; ++t) {
    const ushort* La = L + (t & 1) * 16384;
    const ushort* Lb = La + 8192;
    short8 af[4][2], bf[4][2];
    #pragma unroll
    for (int mi = 0; mi < 4; ++mi)
      #pragma unroll
      for (int ks = 0; ks < 2; ++ks)
        af[mi][ks] = rd_frag(La, wm + mi * 16 + q, ks * 4 + g);
    #pragma unroll
    for (int nj = 0; nj < 4; ++nj)
      #pragma unroll
      for (int ks = 0; ks < 2; ++ks)
        bf[nj][ks] = rd_frag(Lb, wn + nj * 16 + q, ks * 4 + g);
    #pragma unroll
    for (int mi = 0; mi < 4; ++mi)
      #pragma unroll
      for (int nj = 0; nj < 4; ++nj) {
        acc[mi][nj] = MFMA16(af[mi][0], bf[nj][0], acc[mi][nj]);
        acc[mi][nj] = MFMA16(af[mi][1], bf[nj][1], acc[mi][nj]);
      }
    BARRIER();                                      // all waves done reading buf (t&1)
    if (t <= 13) {
      ushort* Ls = L + (t & 1) * 16384;             // overwrite-safe: last read barrier'd above
      stage_half128(Ag + (t + 2) * 64, Ls, tid);
      stage_half128(Bg + (t + 2) * 64, Ls + 8192, tid);
      asm volatile("s_waitcnt vmcnt(8)" ::: "memory");  // tile t+1 landed; t+2's 8 in flight
      BARRIER();
    } else if (t == 14) {
      asm volatile("s_waitcnt vmcnt(0)" ::: "memory");  // tile 15 landed
      BARRIER();
    }
  }
}

// ---------------- GEMM1: qkv = x @ W_qkv^T, LDS-restaged coalesced scatter ----------------
// QF/KF layout: [bh][jt=s>>4][c0=c>>5][lane2(64)][e=c&7]   lane2=((c>>3)&3)*16+(s&15)
// VF layout:    [bh][jc=s>>5][ct=c>>4][lane(64)=((s>>3)&3)*16+(c&15)][e=s&7]
__global__ __launch_bounds__(256, 2) void gemm_qkv(const ushort* __restrict__ xb, const ushort* __restrict__ wqkv,
                                                   ushort* __restrict__ qfbuf, ushort* __restrict__ kfbuf,
                                                   ushort* __restrict__ vfbuf) {
  __shared__ __align__(16) ushort L[32768];   // 64 KB -> 2 blocks/CU
  const int bid = blockIdx.x;                 // 1536 = 8 XCD * (64 m * 3 n); n fastest per XCD
  const int xcd = bid & 7, r0 = bid >> 3;
  const int m0 = (r0 / 3) * 128, n0 = (xcd * 3 + (r0 % 3)) * 128;

  f32x4 acc[4][4];
  #pragma unroll
  for (int i = 0; i < 4; ++i)
    #pragma unroll
    for (int j = 0; j < 4; ++j) acc[i][j] = f32x4{0.f, 0.f, 0.f, 0.f};
  core128(xb, wqkv, m0, n0, L, acc);

  const int lane = threadIdx.x & 63, wave = threadIdx.x >> 6;
  const int g = lane >> 4, q = lane & 15;
  const int wm = (wave >> 1) * 64, wn = (wave & 1) * 64;
  const int s0 = m0 & 2047, bb = m0 >> 11;

  // ---- write phase: C/D (col=q, row=g*4+r) -> LDS [mr][nc ^ ((mr&7)<<4)], bf16
  #pragma unroll
  for (int j = 0; j < 4; ++j) {
    int n = n0 + wn + j * 16 + q;
    int h = n / 192;
    int which = (n - h * 192) >> 6;
    float scl = (which == 0) ? 0.045084222f : 1.0f;   // 1/sqrt(C)*log2(e) folded into Q
    int nc = wn + j * 16 + q;
    #pragma unroll
    for (int i = 0; i < 4; ++i) {
      #pragma unroll
      for (int rr = 0; rr < 4; ++rr) {
        int mr = wm + i * 16 + g * 4 + rr;
        L[mr * 128 + (nc ^ ((mr & 7) << 4))] = f2bf(acc[i][j][rr] * scl);
      }
    }
  }
  __syncthreads();

  // ---- read+store phase: wave w owns n-octet-group [n0+32w, +32) (which/h wave-uniform)
  {
    const int n_g = n0 + wave * 32;
    const int h = n_g / 192, rem = n_g - h * 192, which = rem >> 6;
    const int bh = bb * 16 + h;
    if (which < 2) {
      ushort* dst0 = (which == 0) ? qfbuf : kfbuf;
      const int c0 = (rem & 63) >> 5;
      #pragma unroll
      for (int k = 0; k < 8; ++k) {
        int jt = (s0 >> 4) + k;
        int mr = k * 16 + (lane & 15);
        int nc0 = wave * 32 + (lane >> 4) * 8;
        short8 v = *(const short8*)(L + mr * 128 + (nc0 ^ ((mr & 7) << 4)));
        *(short8*)(dst0 + ((((size_t)bh * 128 + jt) * 2 + c0) * 64 + lane) * 8) = v;
      }
    } else {
      const int ct0 = (rem & 63) >> 4;
      #pragma unroll
      for (int k = 0; k < 8; ++k) {
        int jcr = k >> 1, ct = ct0 + (k & 1);
        int nc = wave * 32 + (k & 1) * 16 + (lane & 15);
        int mrb = jcr * 32 + (lane >> 4) * 8;
        short8 v;
        #pragma unroll
        for (int e = 0; e < 8; ++e) {
          int mr = mrb + e;
          v[e] = (short)L[mr * 128 + (nc ^ ((mr & 7) << 4))];
        }
        int jc = (s0 >> 5) + jcr;
        *(short8*)(vfbuf + ((((size_t)bh * 64 + jc) * 4 + ct) * 64 + lane) * 8) = v;
      }
    }
  }
}

// ---------------- GEMM2: out = attn_out @ W_out^T + b_out + x (f32 out, coalesced) --------
__global__ __launch_bounds__(256, 2) void gemm_out(const ushort* __restrict__ ab, const ushort* __restrict__ wout,
                                                   const ushort* __restrict__ xbb, const float* __restrict__ bias,
                                                   float* __restrict__ out) {
  __shared__ __align__(16) ushort L[32768];
  const int bid = blockIdx.x;                 // 512 = 8 * 64 ; 1 n-panel per XCD
  const int sw = (bid & 7) * 64 + (bid >> 3);
  const int m0 = (sw & 63) * 128, n0 = (sw >> 6) * 128;

  f32x4 acc[4][4];
  #pragma unroll
  for (int i = 0; i < 4; ++i)
    #pragma unroll
    for (int j = 0; j < 4; ++j) acc[i][j] = f32x4{0.f, 0.f, 0.f, 0.f};
  core128(ab, wout, m0, n0, L, acc);

  const int tid = threadIdx.x;
  const int lane = tid & 63, wave = tid >> 6;
  const int g = lane >> 4, q = lane & 15;
  const int wm = (wave >> 1) * 64, wn = (wave & 1) * 64;
  float* Lf = reinterpret_cast<float*>(L);    // 128x128 f32 = 64KB (core128 ended barrier'd)

  // write phase: swz col' = col ^ (bit2(row)<<2) ^ (bit3(row)<<4): 2-way max, float4-safe
  #pragma unroll
  for (int j = 0; j < 4; ++j) {
    int nc = wn + j * 16 + q;
    #pragma unroll
    for (int i = 0; i < 4; ++i) {
      #pragma unroll
      for (int rr = 0; rr < 4; ++rr) {
        int mr = wm + i * 16 + g * 4 + rr;
        int swz = ((mr & 4) << 0) | ((mr & 8) << 1);   // bits {2,4}
        Lf[mr * 128 + (nc ^ swz)] = acc[i][j][rr];
      }
    }
  }
  __syncthreads();

  // read+store phase: fully coalesced float4 stores + bf16 residual + bias
  #pragma unroll
  for (int k = 0; k < 16; ++k) {
    int ci = k * 256 + tid;          // 0..4095 = 128 rows x 32 col-chunks
    int row = ci >> 5, cb = (ci & 31) * 4;
    int swz = ((row & 4) << 0) | ((row & 8) << 1);
    float4 v = *(const float4*)(Lf + row * 128 + (cb ^ swz));
    size_t m = (size_t)(m0 + row);
    int n = n0 + cb;
    ushort4 xr = *(const ushort4*)(xbb + m * 1024 + n);
    float4 bv = *(const float4*)(bias + n);
    float4 o;
    o.x = v.x + bv.x + bf2f(xr.x);
    o.y = v.y + bv.y + bf2f(xr.y);
    o.z = v.z + bv.z + bf2f(xr.z);
    o.w = v.w + bv.w + bf2f(xr.w);
    *(float4*)(out + m * 1024 + n) = o;
  }
}

// ---------------- Flash attention v5 (round-10 version, reverted from T15) -----------------
__device__ __forceinline__ void attn_step(const short8 kf[4][2], const short8 vf[2][4],
                                          const short8 qf[2][2], const short8 onesf,
                                          f32x4 oa[2][4], f32x4 la[2],
                                          ushort* pw0, int g, int q) {
  const f32x4 zed = {0.f, 0.f, 0.f, 0.f};
  #pragma unroll
  for (int t = 0; t < 2; ++t) {
    f32x4 sa[4];
    __builtin_amdgcn_s_setprio(1);
    #pragma unroll
    for (int jt = 0; jt < 4; ++jt) {
      sa[jt] = MFMA16(kf[jt][0], qf[t][0], zed);
      sa[jt] = MFMA16(kf[jt][1], qf[t][1], sa[jt]);
    }
    __builtin_amdgcn_s_setprio(0);
    ushort* pw = pw0 + t * 1152;
    #pragma unroll
    for (int jt = 0; jt < 4; ++jt) {
      uint2 wv;
      wv.x = cvtpk(hw_exp2(sa[jt][0]), hw_exp2(sa[jt][1]));
      wv.y = cvtpk(hw_exp2(sa[jt][2]), hw_exp2(sa[jt][3]));
      *reinterpret_cast<uint2*>(pw + q * 72 + jt * 16 + 4 * g) = wv;
    }
    #pragma unroll
    for (int jc = 0; jc < 2; ++jc) {
      short8 pa = *reinterpret_cast<const short8*>(pw + q * 72 + jc * 32 + g * 8);
      __builtin_amdgcn_s_setprio(1);
      #pragma unroll
      for (int ct = 0; ct < 4; ++ct)
        oa[t][ct] = MFMA16(pa, vf[jc][ct], oa[t][ct]);
      la[t] = MFMA16(pa, onesf, la[t]);
      __builtin_amdgcn_s_setprio(0);
    }
  }
}

__global__ __launch_bounds__(256) void attn_kernel(const ushort* __restrict__ QF, const ushort* __restrict__ KF,
                                                   const ushort* __restrict__ VF, ushort* __restrict__ aout) {
  __shared__ ushort Ps[4][2][16 * 72];
  // grid: 1024 1-D. Per XCD (bid&7): qb cycles fastest -> ~1-2 bh's K/V L2-hot.
  const int bid = blockIdx.x;
  const int xcd = bid & 7, rr = bid >> 3;
  const int qb = rr & 15, bh = xcd + (rr >> 4) * 8;
  const int lane = threadIdx.x & 63, wave = threadIdx.x >> 6;
  const int g = lane >> 4, q = lane & 15;
  const int qt0 = (qb * 4 + wave) * 2;
  const f32x4 zed = {0.f, 0.f, 0.f, 0.f};

  const ushort* Qb = QF + (size_t)bh * 131072 + lane * 8;
  const ushort* Kp = KF + (size_t)bh * 131072 + lane * 8;
  const ushort* Vp = VF + (size_t)bh * 131072 + lane * 8;
  ushort* pw0 = Ps[wave][0];

  short8 onesf;
  #pragma unroll
  for (int e = 0; e < 8; ++e) onesf[e] = (short)0x3F80;

  short8 qf[2][2];
  #pragma unroll
  for (int t = 0; t < 2; ++t)
    #pragma unroll
    for (int c0 = 0; c0 < 2; ++c0)
      qf[t][c0] = *(const short8*)(Qb + ((size_t)(qt0 + t) * 2 + c0) * 512);

  f32x4 oa[2][4], la[2];
  #pragma unroll
  for (int t = 0; t < 2; ++t) {
    la[t] = zed;
    #pragma unroll
    for (int ct = 0; ct < 4; ++ct) oa[t][ct] = zed;
  }

  short8 kfA[4][2], kfB[4][2], vfA[2][4], vfB[2][4];
  #pragma unroll
  for (int jt = 0; jt < 4; ++jt)
    #pragma unroll
    for (int c0 = 0; c0 < 2; ++c0)
      kfA[jt][c0] = *(const short8*)(Kp + ((size_t)jt * 2 + c0) * 512);

  #pragma unroll 1
  for (int i = 0; i < 32; i += 2) {
    #pragma unroll
    for (int jc = 0; jc < 2; ++jc)
      #pragma unroll
      for (int ct = 0; ct < 4; ++ct)
        vfA[jc][ct] = *(const short8*)(Vp + ((size_t)jc * 4 + ct) * 512);
    #pragma unroll
    for (int jt = 0; jt < 4; ++jt)
      #pragma unroll
      for (int c0 = 0; c0 < 2; ++c0)
        kfB[jt][c0] = *(const short8*)(Kp + 4096 + ((size_t)jt * 2 + c0) * 512);

    attn_step(kfA, vfA, qf, onesf, oa, la, pw0, g, q);

    #pragma unroll
    for (int jc = 0; jc < 2; ++jc)
      #pragma unroll
      for (int ct = 0; ct < 4; ++ct)
        vfB[jc][ct] = *(const short8*)(Vp + 4096 + ((size_t)jc * 4 + ct) * 512);
    if (i + 2 < 32) {
      #pragma unroll
      for (int jt = 0; jt < 4; ++jt)
        #pragma unroll
        for (int c0 = 0; c0 < 2; ++c0)
          kfA[jt][c0] = *(const short8*)(Kp + 8192 + ((size_t)jt * 2 + c0) * 512);
    }

    attn_step(kfB, vfB, qf, onesf, oa, la, pw0, g, q);

    Kp += 8192; Vp += 8192;
  }

  const int b = bh >> 4, h = bh & 15;
  #pragma unroll
  for (int t = 0; t < 2; ++t) {
    float inv[4];
    #pragma unroll
    for (int r2 = 0; r2 < 4; ++r2) inv[r2] = 1.0f / la[t][r2];
    #pragma unroll
    for (int ct = 0; ct < 4; ++ct) {
      size_t rowb = (size_t)b * SS + (qt0 + t) * 16 + 4 * g;
      int col = h * DD + ct * 16 + q;
      aout[(rowb + 0) * CC + col] = f2bf(oa[t][ct][0] * inv[0]);
      aout[(rowb + 1) * CC + col] = f2bf(oa[t][ct][1] * inv[1]);
      aout[(rowb + 2) * CC + col] = f2bf(oa[t][ct][2] * inv[2]);
      aout[(rowb + 3) * CC + col] = f2bf(oa[t][ct][3] * inv[3]);
    }
  }
}

extern "C" void kernel_launch(void* const* d_in, const int* in_sizes, int n_in,
                              void* d_out, int out_size, void* d_ws, size_t ws_size,
                              hipStream_t stream) {
  const float* x    = (const float*)d_in[0];   // [4,2048,1024]
  const float* wqkv = (const float*)d_in[1];   // [3072,1024]
  const float* wout = (const float*)d_in[2];   // [1024,1024]
  const float* bias = (const float*)d_in[3];   // [1024]
  float* out = (float*)d_out;

  // workspace carve (ushort elements), total 44M elems = 88MB
  ushort* xb    = (ushort*)d_ws;                   // 8M
  ushort* wqkvb = xb + (size_t)8 * 1024 * 1024;    // 3M
  ushort* woutb = wqkvb + (size_t)3 * 1024 * 1024; // 1M
  ushort* qfbuf = woutb + (size_t)1024 * 1024;     // 8M
  ushort* kfbuf = qfbuf + (size_t)8 * 1024 * 1024; // 8M
  ushort* vfbuf = kfbuf + (size_t)8 * 1024 * 1024; // 8M
  ushort* aout  = vfbuf + (size_t)8 * 1024 * 1024; // 8M

  hipLaunchKernelGGL(cvt3_kernel, dim3(2048), dim3(256), 0, stream,
                     x, xb, 8 * 1024 * 1024 / 4,
                     wqkv, wqkvb, 3 * 1024 * 1024 / 4,
                     wout, woutb, 1024 * 1024 / 4);

  hipLaunchKernelGGL(gemm_qkv, dim3(1536), dim3(256), 0, stream,
                     xb, wqkvb, qfbuf, kfbuf, vfbuf);
  hipLaunchKernelGGL(attn_kernel, dim3(1024), dim3(256), 0, stream,
                     qfbuf, kfbuf, vfbuf, aout);
  hipLaunchKernelGGL(gemm_out, dim3(512), dim3(256), 0, stream,
                     aout, woutb, xb, bias, out);
}